// Round 7
// baseline (533.241 us; speedup 1.0000x reference)
//
#include <hip/hip_runtime.h>
#include <hip/hip_cooperative_groups.h>
#include <math.h>

namespace cg = cooperative_groups;

#define BGR 64          // graphs
#define N0 512          // nodes/graph at level 1
#define E_TOT (BGR*N0*16)
#define EPG 8192        // edge slots per graph, fixed across levels
#define EIT 16          // EPG / 512 threads
#define HID 128
#define NBLK 256        // 4 blocks per graph: (graph, feature-quarter)

struct Params {
  const float* x0; const int* s0; const int* d0;
  const float *W1, *b1, *W2, *b2, *W3, *b3, *Wp, *bp, *L1W, *L1b, *L2W, *L2b;
  float* out;
  float *gout, *xpA, *xpB, *xpC, *dinv, *hp_part;
  int *cnt, *rowptr;
  int2 *edges, *csr;
};

// One cooperative kernel for the whole pipeline. 256 blocks x 512 threads.
// Block b: xcd = b&7 (XCD pin), graph = xcd*8 + (b>>3)/4, q = (b>>3)&3.
// Lead block (q==0) owns per-graph serial work (topology, sort, MLP) and
// holds the readout accumulator z in LDS for the whole kernel.
__global__ __launch_bounds__(512, 2) void k_all(Params p){
  cg::grid_group grid = cg::this_grid();
  extern __shared__ float hl[];          // nper x 32 h-slice (<= 64 KB)
  __shared__ int   sb[512];
  __shared__ int   cur[512];
  __shared__ float dl[512];
  __shared__ float svs[512];
  __shared__ int   sis[512];
  __shared__ float hpl[512];
  __shared__ int   mapb[512];
  __shared__ float4 pmx[16][32];
  __shared__ float4 psm[16][32];
  __shared__ float zr[256];
  __shared__ float h1v[128];
  __shared__ float h2v[64];
  __shared__ float red[2];

  int b = blockIdx.x;
  int xcd = b & 7, slot = b >> 3;
  int graph = xcd*8 + (slot >> 2);
  int q = slot & 3;
  int t = threadIdx.x;
  bool lead = (q == 0);

  // ---- P0: level-1 topology (lead blocks): edge copy + degree + scan +
  //      dinv + CSR fill, edges register-buffered. Also zero z (LDS).
  if (lead){
    if (t < 256) zr[t] = 0.f;
    mapb[t] = 0;                         // mapb doubles as degree counter
    int gbase = graph*N0, ebase = graph*EPG;
    __syncthreads();
    int2 ebuf[EIT];
    #pragma unroll
    for (int it = 0; it < EIT; it++){
      int i = ebase + it*512 + t;
      int2 e = make_int2(p.s0[i], p.d0[i]);
      ebuf[it] = e;
      p.edges[i] = e;
      atomicAdd(&mapb[e.y - gbase], 1);
    }
    __syncthreads();
    int vdeg = mapb[t];
    sb[t] = vdeg; __syncthreads();
    for (int off = 1; off < 512; off <<= 1){
      int add = (t >= off) ? sb[t-off] : 0;
      __syncthreads(); sb[t] += add; __syncthreads();
    }
    int excl = sb[t] - vdeg;
    p.rowptr[gbase + t] = ebase + excl;
    p.cnt[gbase + t] = vdeg;
    cur[t] = excl;
    float dv = rsqrtf((float)vdeg + 1.f);
    dl[t] = dv;
    p.dinv[gbase + t] = dv;
    __syncthreads();
    #pragma unroll
    for (int it = 0; it < EIT; it++){
      int2 e = ebuf[it];
      int sl = e.x - gbase, dc = e.y - gbase;
      int pos = atomicAdd(&cur[dc], 1);
      p.csr[ebase + pos] = make_int2(e.x, __float_as_int(dl[sl]*dl[dc]));
    }
  }
  grid.sync();

  for (int lev = 0; lev < 3; lev++){
    int nper = 512 >> lev;
    int k = nper >> 1;
    bool lastlev = (lev == 2);
    const float* xin = (lev == 0) ? p.x0 : ((lev == 1) ? p.xpA : p.xpB);
    const float* W   = (lev == 0) ? p.W1 : ((lev == 1) ? p.W2 : p.W3);
    const float* bia = (lev == 0) ? p.b1 : ((lev == 1) ? p.b2 : p.b3);
    float* xp        = (lev == 0) ? p.xpA : p.xpB;    // lev2 never writes xp
    int fin = (lev == 0) ? 10 : HID;
    int gbase = graph*nper, ebase = graph*EPG, gb2 = graph*k;

    // ---- level phase (all 256 blocks): h-slice GEMM into LDS, then
    //      GCN gather from LDS; fused bias+relu + hp quarter-partial.
    {
      int fp = t & 31, f = q*32 + fp;
      if (fin == 10){
        float wcol[10];
        #pragma unroll
        for (int kk2 = 0; kk2 < 10; kk2++) wcol[kk2] = W[kk2*HID + f];
        for (int n = t >> 5; n < nper; n += 16){
          const float* xr = xin + (gbase + n)*10;
          float acc = 0.f;
          #pragma unroll
          for (int kk2 = 0; kk2 < 10; kk2++) acc += xr[kk2]*wcol[kk2];
          hl[n*32 + fp] = acc;
        }
      } else {
        for (int n = t >> 5; n < nper; n += 16){
          const float* xr = xin + (gbase + n)*HID;
          float acc = 0.f;
          #pragma unroll 8
          for (int kk2 = 0; kk2 < HID; kk2++) acc += xr[kk2]*W[kk2*HID + f];
          hl[n*32 + fp] = acc;
        }
      }
      __syncthreads();
      const float4* hl4 = (const float4*)hl;
      float4* gout4 = (float4*)p.gout;
      int l = t & 7, grp = t >> 3;
      float4 bb = ((const float4*)bia)[q*8 + l];
      float4 wp = ((const float4*)p.Wp)[q*8 + l];
      for (int nl = grp; nl < nper; nl += 64){
        int node = gbase + nl;
        int start = p.rowptr[node], c = p.cnt[node];
        float4 acc = make_float4(0.f,0.f,0.f,0.f);
        for (int j = 0; j < c; j++){
          int2 e = p.csr[start + j];
          float wgt = __int_as_float(e.y);
          float4 hv = hl4[(e.x - gbase)*8 + l];
          acc.x += wgt*hv.x; acc.y += wgt*hv.y;
          acc.z += wgt*hv.z; acc.w += wgt*hv.w;
        }
        float di = p.dinv[node], dd = di*di;
        float4 hs = hl4[nl*8 + l];
        float4 v;
        v.x = fmaxf(acc.x + hs.x*dd + bb.x, 0.f);
        v.y = fmaxf(acc.y + hs.y*dd + bb.y, 0.f);
        v.z = fmaxf(acc.z + hs.z*dd + bb.z, 0.f);
        v.w = fmaxf(acc.w + hs.w*dd + bb.w, 0.f);
        gout4[node*32 + q*8 + l] = v;
        float contrib = v.x*wp.x + v.y*wp.y + v.z*wp.z + v.w*wp.w;
        #pragma unroll
        for (int off = 4; off; off >>= 1) contrib += __shfl_down(contrib, off, 8);
        if (l == 0) p.hp_part[q*32768 + node] = contrib;
      }
    }
    grid.sync();

    // ---- mega phase (lead blocks): score -> sort -> pool/readout ->
    //      relabel + next topology (or MLP on the last level).
    if (lead){
      bool act = t < nper;
      if (act){
        int node = gbase + t;
        hpl[t] = p.hp_part[node] + p.hp_part[32768 + node]
               + p.hp_part[65536 + node] + p.hp_part[98304 + node];
      }
      __syncthreads();
      float v = 0.f; int idx = t;
      if (act){
        int start = p.rowptr[gbase + t], c = p.cnt[gbase + t];
        float a = 0.f;
        for (int j = 0; j < c; j++){
          int2 e = p.csr[start + j];
          a += __int_as_float(e.y) * hpl[e.x - gbase];
        }
        float di = p.dinv[gbase + t];
        v = tanhf(a + hpl[t]*di*di + p.bp[0]);
      }
      // bitonic sort desc (ties: lower index first, matches jax top_k)
      for (int kk = 2; kk <= nper; kk <<= 1){
        for (int jj = kk >> 1; jj > 0; jj >>= 1){
          if (jj >= 64){
            if (act){ svs[t] = v; sis[t] = idx; }
            __syncthreads();
            if (act){
              int pr = t ^ jj;
              float pv = svs[pr]; int pi = sis[pr];
              bool amLower = (t & jj) == 0;
              bool dirDesc = (t & kk) == 0;
              bool betterMine = (v > pv) || (v == pv && idx < pi);
              if ((amLower == dirDesc) != betterMine){ v = pv; idx = pi; }
            }
            __syncthreads();
          } else if (act){
            float pv = __shfl_xor(v, jj);
            int   pi = __shfl_xor(idx, jj);
            bool amLower = (t & jj) == 0;
            bool dirDesc = (t & kk) == 0;
            bool betterMine = (v > pv) || (v == pv && idx < pi);
            if ((amLower == dirDesc) != betterMine){ v = pv; idx = pi; }
          }
        }
      }
      if (act){ svs[t] = v; sis[t] = idx; }
      __syncthreads();
      // pooled rows + readout partials
      int l = t & 31, j0 = t >> 5;
      float4 mx = make_float4(-INFINITY,-INFINITY,-INFINITY,-INFINITY);
      float4 sm = make_float4(0.f,0.f,0.f,0.f);
      const float4* gout4c = (const float4*)p.gout;
      float4* xp4 = (float4*)xp;
      for (int j = j0; j < k; j += 16){
        float val = svs[j]; int row = sis[j];
        float4 hv = gout4c[(gbase + row)*32 + l];
        float4 o = make_float4(hv.x*val, hv.y*val, hv.z*val, hv.w*val);
        if (!lastlev) xp4[(gb2 + j)*32 + l] = o;
        mx.x = fmaxf(mx.x, o.x); mx.y = fmaxf(mx.y, o.y);
        mx.z = fmaxf(mx.z, o.z); mx.w = fmaxf(mx.w, o.w);
        sm.x += o.x; sm.y += o.y; sm.z += o.z; sm.w += o.w;
      }
      pmx[j0][l] = mx; psm[j0][l] = sm;
      __syncthreads();
      if (t < 32){
        float4 M = pmx[0][t], S = psm[0][t];
        #pragma unroll
        for (int q2 = 1; q2 < 16; q2++){
          float4 m2 = pmx[q2][t], s2 = psm[q2][t];
          M.x = fmaxf(M.x, m2.x); M.y = fmaxf(M.y, m2.y);
          M.z = fmaxf(M.z, m2.z); M.w = fmaxf(M.w, m2.w);
          S.x += s2.x; S.y += s2.y; S.z += s2.z; S.w += s2.w;
        }
        float ki = 1.f/(float)k;
        zr[t*4+0] += M.x; zr[t*4+1] += M.y; zr[t*4+2] += M.z; zr[t*4+3] += M.w;
        zr[128+t*4+0] += S.x*ki; zr[128+t*4+1] += S.y*ki;
        zr[128+t*4+2] += S.z*ki; zr[128+t*4+3] += S.w*ki;
      }
      if (!lastlev){
        // mapping
        if (act) mapb[t] = -1;
        if (t < k) sb[t] = 0;
        __syncthreads();
        if (t < k) mapb[sis[t]] = t;
        __syncthreads();
        // relabel (register-buffered) + next degree count
        int2 ebuf[EIT];
        #pragma unroll
        for (int it = 0; it < EIT; it++){
          int i = ebase + it*512 + t;
          int2 e = p.edges[i];
          int2 ne = make_int2(-1, 0);
          if (e.x >= 0){
            int ns = mapb[e.x - gbase], nd = mapb[e.y - gbase];
            if (ns >= 0 && nd >= 0){
              ne = make_int2(gb2 + ns, gb2 + nd);
              atomicAdd(&sb[nd], 1);
            }
          }
          ebuf[it] = ne;
          p.edges[i] = ne;
        }
        __syncthreads();
        // scan new degrees -> rowptr/cnt/dinv/cursor
        int vdeg = (t < k) ? sb[t] : 0;
        for (int off = 1; off < k; off <<= 1){
          int add = (t >= off && t < k) ? sb[t-off] : 0;
          __syncthreads();
          if (t < k) sb[t] += add;
          __syncthreads();
        }
        if (t < k){
          int excl = sb[t] - vdeg;
          p.rowptr[gb2 + t] = ebase + excl;
          p.cnt[gb2 + t] = vdeg;
          cur[t] = excl;
          float dv = rsqrtf((float)vdeg + 1.f);
          dl[t] = dv;
          p.dinv[gb2 + t] = dv;
        }
        __syncthreads();
        // next-level CSR fill
        #pragma unroll
        for (int it = 0; it < EIT; it++){
          int2 e = ebuf[it];
          if (e.x >= 0){
            int sl = e.x - gb2, dc = e.y - gb2;
            int pos = atomicAdd(&cur[dc], 1);
            p.csr[ebase + pos] = make_int2(e.x, __float_as_int(dl[sl]*dl[dc]));
          }
        }
      } else {
        // ---- fused MLP + log_softmax on z (LDS) ----
        __syncthreads();
        if (t < 128){
          float a = p.L1b[t];
          for (int i = 0; i < 256; i++) a += zr[i]*p.L1W[i*128 + t];
          h1v[t] = fmaxf(a, 0.f);
        }
        __syncthreads();
        if (t < 64){
          float a = p.L2b[t];
          for (int i = 0; i < 128; i++) a += h1v[i]*p.L2W[i*64 + t];
          h2v[t] = fmaxf(a, 0.f);
        }
        __syncthreads();
        if (t == 0){
          float mxv = -INFINITY;
          for (int i = 0; i < 64; i++) mxv = fmaxf(mxv, h2v[i]);
          float s = 0.f;
          for (int i = 0; i < 64; i++) s += expf(h2v[i] - mxv);
          red[0] = mxv; red[1] = logf(s);
        }
        __syncthreads();
        if (t < 64) p.out[graph*64 + t] = h2v[t] - red[0] - red[1];
      }
    }
    if (lev < 2) grid.sync();
  }
}

extern "C" void kernel_launch(void* const* d_in, const int* in_sizes, int n_in,
                              void* d_out, int out_size, void* d_ws, size_t ws_size,
                              hipStream_t stream){
  (void)in_sizes; (void)n_in; (void)out_size; (void)ws_size;
  Params P;
  P.x0  = (const float*)d_in[0];
  P.s0  = (const int*)  d_in[1];
  P.d0  = (const int*)  d_in[2];
  P.W1  = (const float*)d_in[3];  P.b1  = (const float*)d_in[4];
  P.W2  = (const float*)d_in[5];  P.b2  = (const float*)d_in[6];
  P.W3  = (const float*)d_in[7];  P.b3  = (const float*)d_in[8];
  P.Wp  = (const float*)d_in[9];  P.bp  = (const float*)d_in[10];
  P.L1W = (const float*)d_in[11]; P.L1b = (const float*)d_in[12];
  P.L2W = (const float*)d_in[13]; P.L2b = (const float*)d_in[14];
  P.out = (float*)d_out;

  float* w = (float*)d_ws;
  P.gout    = w; w += 32768*HID;         // 16 MB
  P.xpA     = w; w += 16384*HID;         // level-1 pool out
  P.xpB     = w; w += 8192*HID;          // level-2 pool out
  P.xpC     = w; w += 4096*HID;          // unused (kept for layout clarity)
  P.dinv    = w; w += 32768;
  P.hp_part = w; w += 4*32768;
  P.cnt     = (int*)w; w += 32768;
  P.rowptr  = (int*)w; w += 32768;
  P.edges   = (int2*)w; w += 2*E_TOT;
  P.csr     = (int2*)w; w += 2*E_TOT;

  void* args[] = { (void*)&P };
  hipLaunchCooperativeKernel((const void*)k_all, dim3(NBLK), dim3(512),
                             args, 65536, stream);
}

// Round 8
// 301.546 us; speedup vs baseline: 1.7684x; 1.7684x over previous
//
#include <hip/hip_runtime.h>
#include <math.h>

#define BGR 64          // graphs
#define N0 512          // nodes/graph at level 1
#define E_TOT (BGR*N0*16)
#define EPG 8192        // edge slots per graph, fixed across levels
#define EIT 16          // EPG / 512 threads
#define HID 128

// ---- XCD heuristic: blockIdx % 8 -> XCD; graph g pinned to XCD g/8.

// Per-graph level-1 topology: edge copy + degree (LDS atomics) + scan + dinv
// + CSR fill (edges register-buffered). Also zeroes z.
__global__ __launch_bounds__(512) void k_topo0(
    const int* __restrict__ s0, const int* __restrict__ d0,
    int2* __restrict__ edges, int* __restrict__ cnt, int* __restrict__ rowptr,
    float* __restrict__ dinv, int2* __restrict__ csr, float* __restrict__ z){
  __shared__ int   deg[512];
  __shared__ int   sb[512];
  __shared__ int   cur[512];
  __shared__ float dl[512];
  int g = (blockIdx.x & 7)*8 + (blockIdx.x >> 3);
  int t = threadIdx.x;
  int gbase = g*N0, ebase = g*EPG;
  deg[t] = 0;
  if (t < 256) z[g*256 + t] = 0.f;
  __syncthreads();
  int2 ebuf[EIT];
  #pragma unroll
  for (int it = 0; it < EIT; it++){
    int i = ebase + it*512 + t;
    int2 e = make_int2(s0[i], d0[i]);
    ebuf[it] = e;
    edges[i] = e;
    atomicAdd(&deg[e.y - gbase], 1);
  }
  __syncthreads();
  int vdeg = deg[t];
  sb[t] = vdeg; __syncthreads();
  for (int off = 1; off < 512; off <<= 1){
    int add = (t >= off) ? sb[t-off] : 0;
    __syncthreads(); sb[t] += add; __syncthreads();
  }
  int excl = sb[t] - vdeg;
  rowptr[gbase + t] = ebase + excl;
  cnt[gbase + t] = vdeg;
  cur[t] = excl;
  float dv = rsqrtf((float)vdeg + 1.f);
  dl[t] = dv;
  dinv[gbase + t] = dv;
  __syncthreads();
  #pragma unroll
  for (int it = 0; it < EIT; it++){
    int2 e = ebuf[it];
    int sl = e.x - gbase, dc = e.y - gbase;
    int pos = atomicAdd(&cur[dc], 1);
    csr[ebase + pos] = make_int2(e.x, __float_as_int(dl[sl]*dl[dc]));
  }
}

// Level-1 fused GEMM+gather: block = (graph, feature-quarter). Computes the
// 512x32 h-slice in LDS (64 KB dynamic) from x (fin=10), then gathers
// neighbors from LDS. Writes gout quarter + hp quarter-partial.
__global__ __launch_bounds__(512) void k_l1_fused(
    const float* __restrict__ x, const float* __restrict__ W1,
    const int2* __restrict__ csr, const int* __restrict__ rowptr,
    const int* __restrict__ cnt, const float* __restrict__ dinv,
    const float* __restrict__ b1, const float* __restrict__ Wp,
    float4* __restrict__ gout4, float* __restrict__ hp_part){
  extern __shared__ float hl[];   // 512 nodes x 32 feats = 64 KB
  int b = blockIdx.x;
  int xcd = b & 7, idx = b >> 3;
  int graph = xcd*8 + (idx >> 2);
  int qf = idx & 3;
  int t = threadIdx.x;
  int gbase = graph*N0;
  int fp = t & 31;
  int f = qf*32 + fp;
  float wcol[10];
  #pragma unroll
  for (int k = 0; k < 10; k++) wcol[k] = W1[k*HID + f];
  for (int n = t >> 5; n < N0; n += 16){
    const float* xr = x + (gbase + n)*10;
    float acc = 0.f;
    #pragma unroll
    for (int k = 0; k < 10; k++) acc += xr[k]*wcol[k];
    hl[n*32 + fp] = acc;
  }
  __syncthreads();
  const float4* hl4 = (const float4*)hl;
  int l = t & 7, grp = t >> 3;
  float4 bb = ((const float4*)b1)[qf*8 + l];
  float4 wp = ((const float4*)Wp)[qf*8 + l];
  for (int nl = grp; nl < N0; nl += 64){
    int node = gbase + nl;
    int start = rowptr[node], c = cnt[node];
    float4 acc = make_float4(0.f,0.f,0.f,0.f);
    for (int j = 0; j < c; j++){
      int2 e = csr[start + j];
      float wgt = __int_as_float(e.y);
      float4 hv = hl4[(e.x - gbase)*8 + l];
      acc.x += wgt*hv.x; acc.y += wgt*hv.y; acc.z += wgt*hv.z; acc.w += wgt*hv.w;
    }
    float di = dinv[node], dd = di*di;
    float4 hs = hl4[nl*8 + l];
    float4 v;
    v.x = fmaxf(acc.x + hs.x*dd + bb.x, 0.f);
    v.y = fmaxf(acc.y + hs.y*dd + bb.y, 0.f);
    v.z = fmaxf(acc.z + hs.z*dd + bb.z, 0.f);
    v.w = fmaxf(acc.w + hs.w*dd + bb.w, 0.f);
    gout4[node*32 + qf*8 + l] = v;
    float contrib = v.x*wp.x + v.y*wp.y + v.z*wp.z + v.w*wp.w;
    #pragma unroll
    for (int off = 4; off; off >>= 1) contrib += __shfl_down(contrib, off, 8);
    if (l == 0) hp_part[qf*32768 + node] = contrib;
  }
}

// Levels 2/3 fused GEMM+gather (fin=128): stage W quarter (16 KB) in LDS,
// compute nper x 32 h-slice in LDS, gather neighbors from LDS.
// dyn LDS = (4096 + nper*32) floats.
__global__ __launch_bounds__(512) void k_lx_fused(
    const float* __restrict__ x, const float* __restrict__ W,
    const int2* __restrict__ csr, const int* __restrict__ rowptr,
    const int* __restrict__ cnt, const float* __restrict__ dinv,
    const float* __restrict__ bia, const float* __restrict__ Wp,
    float4* __restrict__ gout4, float* __restrict__ hp_part, int nper){
  extern __shared__ float smem[];
  float* wl = smem;                 // 128 x 32 W quarter
  float* hl = smem + 4096;          // nper x 32 h-slice
  int b = blockIdx.x;
  int xcd = b & 7, idx = b >> 3;
  int graph = xcd*8 + (idx >> 2);
  int qf = idx & 3;
  int t = threadIdx.x;
  int gbase = graph*nper;
  int fp = t & 31, f = qf*32 + fp;
  for (int kk = t >> 5; kk < 128; kk += 16) wl[kk*32 + fp] = W[kk*HID + f];
  __syncthreads();
  // phase A: h-slice GEMM (x row read as float4, W from LDS broadcast)
  for (int n = t >> 5; n < nper; n += 16){
    const float4* xr = (const float4*)(x + (gbase + n)*HID);
    float acc = 0.f;
    #pragma unroll 8
    for (int kk = 0; kk < 32; kk++){
      float4 xv = xr[kk];
      acc += xv.x*wl[(kk*4+0)*32 + fp] + xv.y*wl[(kk*4+1)*32 + fp]
           + xv.z*wl[(kk*4+2)*32 + fp] + xv.w*wl[(kk*4+3)*32 + fp];
    }
    hl[n*32 + fp] = acc;
  }
  __syncthreads();
  // phase B: gather from LDS
  const float4* hl4 = (const float4*)hl;
  int l = t & 7, grp = t >> 3;
  float4 bb = ((const float4*)bia)[qf*8 + l];
  float4 wp = ((const float4*)Wp)[qf*8 + l];
  for (int nl = grp; nl < nper; nl += 64){
    int node = gbase + nl;
    int start = rowptr[node], c = cnt[node];
    float4 acc = make_float4(0.f,0.f,0.f,0.f);
    for (int j = 0; j < c; j++){
      int2 e = csr[start + j];
      float wgt = __int_as_float(e.y);
      float4 hv = hl4[(e.x - gbase)*8 + l];
      acc.x += wgt*hv.x; acc.y += wgt*hv.y; acc.z += wgt*hv.z; acc.w += wgt*hv.w;
    }
    float di = dinv[node], dd = di*di;
    float4 hs = hl4[nl*8 + l];
    float4 v;
    v.x = fmaxf(acc.x + hs.x*dd + bb.x, 0.f);
    v.y = fmaxf(acc.y + hs.y*dd + bb.y, 0.f);
    v.z = fmaxf(acc.z + hs.z*dd + bb.z, 0.f);
    v.w = fmaxf(acc.w + hs.w*dd + bb.w, 0.f);
    gout4[node*32 + qf*8 + l] = v;
    float contrib = v.x*wp.x + v.y*wp.y + v.z*wp.z + v.w*wp.w;
    #pragma unroll
    for (int off = 4; off; off >>= 1) contrib += __shfl_down(contrib, off, 8);
    if (l == 0) hp_part[qf*32768 + node] = contrib;
  }
}

// Per-graph mega: score (sum 4 hp quarter-partials) -> hybrid shfl/LDS
// bitonic top-k -> pooled rows + fused readout -> relabel + next topology.
// On the last level: fused readout finalize + MLP + log_softmax.
__global__ __launch_bounds__(512) void k_mega(
    const float4* __restrict__ gout4, const float* __restrict__ hp_part,
    int2* __restrict__ csr, int* __restrict__ rowptr, int* __restrict__ cnt,
    float* __restrict__ dinv, const float* __restrict__ bp,
    int2* __restrict__ edges, float4* __restrict__ xpool4,
    float* __restrict__ z, int nper, int lastlev,
    const float* __restrict__ L1W, const float* __restrict__ L1b,
    const float* __restrict__ L2W, const float* __restrict__ L2b,
    float* __restrict__ out){
  __shared__ float sv[512];
  __shared__ int   si[512];
  __shared__ float hpl[512];
  __shared__ int   map[512];
  __shared__ int   sb[512];
  __shared__ int   cur[256];
  __shared__ float dl[256];
  __shared__ float4 pmx[16][32];
  __shared__ float4 psm[16][32];
  __shared__ float zr[256];
  __shared__ float h1[128];
  __shared__ float h2[64];
  __shared__ float red[2];
  int g = (blockIdx.x & 7)*8 + (blockIdx.x >> 3);
  int t = threadIdx.x;
  int k = nper >> 1;
  int gbase = g*nper, ebase = g*EPG, gb2 = g*k;
  bool act = t < nper;
  // ---- score ----
  if (act){
    int node = gbase + t;
    hpl[t] = hp_part[node] + hp_part[32768 + node]
           + hp_part[65536 + node] + hp_part[98304 + node];
  }
  __syncthreads();
  float v = 0.f; int idx = t;
  if (act){
    int start = rowptr[gbase + t], c = cnt[gbase + t];
    float a = 0.f;
    for (int j = 0; j < c; j++){
      int2 e = csr[start + j];
      a += __int_as_float(e.y) * hpl[e.x - gbase];
    }
    float di = dinv[gbase + t];
    v = tanhf(a + hpl[t]*di*di + bp[0]);
  }
  // ---- bitonic sort desc (ties: lower index). jj<64 via shfl ----
  for (int kk = 2; kk <= nper; kk <<= 1){
    for (int jj = kk >> 1; jj > 0; jj >>= 1){
      if (jj >= 64){
        if (act){ sv[t] = v; si[t] = idx; }
        __syncthreads();
        if (act){
          int p = t ^ jj;
          float pv = sv[p]; int pi = si[p];
          bool amLower = (t & jj) == 0;
          bool dirDesc = (t & kk) == 0;
          bool betterMine = (v > pv) || (v == pv && idx < pi);
          if ((amLower == dirDesc) != betterMine){ v = pv; idx = pi; }
        }
        __syncthreads();
      } else if (act){
        float pv = __shfl_xor(v, jj);
        int   pi = __shfl_xor(idx, jj);
        bool amLower = (t & jj) == 0;
        bool dirDesc = (t & kk) == 0;
        bool betterMine = (v > pv) || (v == pv && idx < pi);
        if ((amLower == dirDesc) != betterMine){ v = pv; idx = pi; }
      }
    }
  }
  if (act){ sv[t] = v; si[t] = idx; }
  __syncthreads();
  // ---- pooled rows + readout partials ----
  int l = t & 31, j0 = t >> 5;
  float4 mx = make_float4(-INFINITY,-INFINITY,-INFINITY,-INFINITY);
  float4 sm = make_float4(0.f,0.f,0.f,0.f);
  for (int j = j0; j < k; j += 16){
    float val = sv[j]; int row = si[j];
    float4 hv = gout4[(gbase + row)*32 + l];
    float4 o = make_float4(hv.x*val, hv.y*val, hv.z*val, hv.w*val);
    if (!lastlev) xpool4[(gb2 + j)*32 + l] = o;
    mx.x = fmaxf(mx.x, o.x); mx.y = fmaxf(mx.y, o.y);
    mx.z = fmaxf(mx.z, o.z); mx.w = fmaxf(mx.w, o.w);
    sm.x += o.x; sm.y += o.y; sm.z += o.z; sm.w += o.w;
  }
  pmx[j0][l] = mx; psm[j0][l] = sm;
  __syncthreads();
  if (t < 32){
    float4 M = pmx[0][t], S = psm[0][t];
    #pragma unroll
    for (int q = 1; q < 16; q++){
      float4 m2 = pmx[q][t], s2 = psm[q][t];
      M.x = fmaxf(M.x, m2.x); M.y = fmaxf(M.y, m2.y);
      M.z = fmaxf(M.z, m2.z); M.w = fmaxf(M.w, m2.w);
      S.x += s2.x; S.y += s2.y; S.z += s2.z; S.w += s2.w;
    }
    float ki = 1.f/(float)k;
    float* zp = z + g*256;
    if (!lastlev){
      zp[t*4+0] += M.x; zp[t*4+1] += M.y; zp[t*4+2] += M.z; zp[t*4+3] += M.w;
      zp[128+t*4+0] += S.x*ki; zp[128+t*4+1] += S.y*ki;
      zp[128+t*4+2] += S.z*ki; zp[128+t*4+3] += S.w*ki;
    } else {
      zr[t*4+0] = zp[t*4+0] + M.x; zr[t*4+1] = zp[t*4+1] + M.y;
      zr[t*4+2] = zp[t*4+2] + M.z; zr[t*4+3] = zp[t*4+3] + M.w;
      zr[128+t*4+0] = zp[128+t*4+0] + S.x*ki;
      zr[128+t*4+1] = zp[128+t*4+1] + S.y*ki;
      zr[128+t*4+2] = zp[128+t*4+2] + S.z*ki;
      zr[128+t*4+3] = zp[128+t*4+3] + S.w*ki;
    }
  }
  if (lastlev){
    __syncthreads();
    if (t < 128){
      float a = L1b[t];
      for (int i = 0; i < 256; i++) a += zr[i]*L1W[i*128 + t];
      h1[t] = fmaxf(a, 0.f);
    }
    __syncthreads();
    if (t < 64){
      float a = L2b[t];
      for (int i = 0; i < 128; i++) a += h1[i]*L2W[i*64 + t];
      h2[t] = fmaxf(a, 0.f);
    }
    __syncthreads();
    if (t == 0){
      float mxv = -INFINITY;
      for (int i = 0; i < 64; i++) mxv = fmaxf(mxv, h2[i]);
      float s = 0.f;
      for (int i = 0; i < 64; i++) s += expf(h2[i] - mxv);
      red[0] = mxv; red[1] = logf(s);
    }
    __syncthreads();
    if (t < 64) out[g*64 + t] = h2[t] - red[0] - red[1];
    return;
  }
  // ---- mapping ----
  if (act) map[t] = -1;
  if (t < k) sb[t] = 0;
  __syncthreads();
  if (t < k) map[si[t]] = t;
  __syncthreads();
  // ---- relabel (register-buffered) + next degree count ----
  int2 ebuf[EIT];
  #pragma unroll
  for (int it = 0; it < EIT; it++){
    int i = ebase + it*512 + t;
    int2 e = edges[i];
    int2 ne = make_int2(-1, 0);
    if (e.x >= 0){
      int ns = map[e.x - gbase], nd = map[e.y - gbase];
      if (ns >= 0 && nd >= 0){
        ne = make_int2(gb2 + ns, gb2 + nd);
        atomicAdd(&sb[nd], 1);
      }
    }
    ebuf[it] = ne;
    edges[i] = ne;
  }
  __syncthreads();
  // ---- scan new degrees -> rowptr/cnt/dinv/cursor ----
  int vdeg = (t < k) ? sb[t] : 0;
  for (int off = 1; off < k; off <<= 1){
    int add = (t >= off && t < k) ? sb[t-off] : 0;
    __syncthreads();
    if (t < k) sb[t] += add;
    __syncthreads();
  }
  if (t < k){
    int excl = sb[t] - vdeg;
    rowptr[gb2 + t] = ebase + excl;
    cnt[gb2 + t] = vdeg;
    cur[t] = excl;
    float dv = rsqrtf((float)vdeg + 1.f);
    dl[t] = dv;
    dinv[gb2 + t] = dv;
  }
  __syncthreads();
  // ---- next-level CSR fill ----
  #pragma unroll
  for (int it = 0; it < EIT; it++){
    int2 e = ebuf[it];
    if (e.x >= 0){
      int sl = e.x - gb2, dc = e.y - gb2;
      int pos = atomicAdd(&cur[dc], 1);
      csr[ebase + pos] = make_int2(e.x, __float_as_int(dl[sl]*dl[dc]));
    }
  }
}

extern "C" void kernel_launch(void* const* d_in, const int* in_sizes, int n_in,
                              void* d_out, int out_size, void* d_ws, size_t ws_size,
                              hipStream_t stream){
  (void)in_sizes; (void)n_in; (void)out_size; (void)ws_size;
  const float* x0  = (const float*)d_in[0];
  const int*   s0  = (const int*)  d_in[1];
  const int*   d0  = (const int*)  d_in[2];
  const float* W1  = (const float*)d_in[3];  const float* b1 = (const float*)d_in[4];
  const float* W2  = (const float*)d_in[5];  const float* b2 = (const float*)d_in[6];
  const float* W3  = (const float*)d_in[7];  const float* b3 = (const float*)d_in[8];
  const float* Wp  = (const float*)d_in[9];  const float* bp = (const float*)d_in[10];
  const float* L1W = (const float*)d_in[11]; const float* L1b = (const float*)d_in[12];
  const float* L2W = (const float*)d_in[13]; const float* L2b = (const float*)d_in[14];
  float* out = (float*)d_out;

  float* w = (float*)d_ws;
  float* gout  = w; w += 32768*HID;
  float* xpA   = w; w += 16384*HID;          // level-1 pool out
  float* xpB   = w; w += 8192*HID;           // level-2 pool out
  float* dinvv = w; w += 32768;
  float* hppt  = w; w += 4*32768;            // hp quarter-partials
  float* z     = w; w += BGR*256;
  int* cnt     = (int*)w; w += 32768;
  int* rowptr  = (int*)w; w += 32768;
  int2* edges  = (int2*)w; w += 2*E_TOT;
  int2* csr    = (int2*)w; w += 2*E_TOT;

  k_topo0<<<BGR, 512, 0, stream>>>(s0, d0, edges, cnt, rowptr, dinvv, csr, z);

  // level 1: 512 -> 256
  k_l1_fused<<<256, 512, 65536, stream>>>(x0, W1, csr, rowptr, cnt, dinvv,
                                          b1, Wp, (float4*)gout, hppt);
  k_mega<<<BGR, 512, 0, stream>>>((const float4*)gout, hppt, csr, rowptr, cnt,
                                  dinvv, bp, edges, (float4*)xpA, z, 512, 0,
                                  L1W, L1b, L2W, L2b, out);
  // level 2: 256 -> 128 (fused gemm+gather, W staged in LDS)
  k_lx_fused<<<256, 512, (4096 + 256*32)*4, stream>>>(xpA, W2, csr, rowptr, cnt,
                                                      dinvv, b2, Wp, (float4*)gout,
                                                      hppt, 256);
  k_mega<<<BGR, 512, 0, stream>>>((const float4*)gout, hppt, csr, rowptr, cnt,
                                  dinvv, bp, edges, (float4*)xpB, z, 256, 0,
                                  L1W, L1b, L2W, L2b, out);
  // level 3: 128 -> 64 (+ fused readout/MLP/log_softmax)
  k_lx_fused<<<256, 512, (4096 + 128*32)*4, stream>>>(xpB, W3, csr, rowptr, cnt,
                                                      dinvv, b3, Wp, (float4*)gout,
                                                      hppt, 128);
  k_mega<<<BGR, 512, 0, stream>>>((const float4*)gout, hppt, csr, rowptr, cnt,
                                  dinvv, bp, edges, (float4*)xpA, z, 128, 1,
                                  L1W, L1b, L2W, L2b, out);
}

// Round 9
// 266.670 us; speedup vs baseline: 1.9996x; 1.1308x over previous
//
#include <hip/hip_runtime.h>
#include <math.h>

#define BGR 64          // graphs
#define N0 512          // nodes/graph at level 1
#define E_TOT (BGR*N0*16)
#define EPG 8192        // edge slots per graph, fixed across levels
#define EIT 16          // EPG / 512 threads
#define HID 128

// ---- XCD heuristic: blockIdx % 8 -> XCD; graph g pinned to XCD g/8.

// Per-graph level-1 topology: edge copy + degree (LDS atomics) + scan + dinv
// + CSR fill (edges register-buffered). Also zeroes z.
__global__ __launch_bounds__(512) void k_topo0(
    const int* __restrict__ s0, const int* __restrict__ d0,
    int2* __restrict__ edges, int* __restrict__ cnt, int* __restrict__ rowptr,
    float* __restrict__ dinv, int2* __restrict__ csr, float* __restrict__ z){
  __shared__ int   deg[512];
  __shared__ int   sb[512];
  __shared__ int   cur[512];
  __shared__ float dl[512];
  int g = (blockIdx.x & 7)*8 + (blockIdx.x >> 3);
  int t = threadIdx.x;
  int gbase = g*N0, ebase = g*EPG;
  deg[t] = 0;
  if (t < 256) z[g*256 + t] = 0.f;
  __syncthreads();
  int2 ebuf[EIT];
  #pragma unroll
  for (int it = 0; it < EIT; it++){
    int i = ebase + it*512 + t;
    int2 e = make_int2(s0[i], d0[i]);
    ebuf[it] = e;
    edges[i] = e;
    atomicAdd(&deg[e.y - gbase], 1);
  }
  __syncthreads();
  int vdeg = deg[t];
  sb[t] = vdeg; __syncthreads();
  for (int off = 1; off < 512; off <<= 1){
    int add = (t >= off) ? sb[t-off] : 0;
    __syncthreads(); sb[t] += add; __syncthreads();
  }
  int excl = sb[t] - vdeg;
  rowptr[gbase + t] = ebase + excl;
  cnt[gbase + t] = vdeg;
  cur[t] = excl;
  float dv = rsqrtf((float)vdeg + 1.f);
  dl[t] = dv;
  dinv[gbase + t] = dv;
  __syncthreads();
  #pragma unroll
  for (int it = 0; it < EIT; it++){
    int2 e = ebuf[it];
    int sl = e.x - gbase, dc = e.y - gbase;
    int pos = atomicAdd(&cur[dc], 1);
    csr[ebase + pos] = make_int2(e.x, __float_as_int(dl[sl]*dl[dc]));
  }
}

// Level-1 fused GEMM+gather: block = (graph, feature-quarter). Computes the
// 512x32 h-slice in LDS (64 KB dynamic) from x (fin=10), then gathers
// neighbors from LDS. Writes gout quarter + hp quarter-partial.
__global__ __launch_bounds__(512) void k_l1_fused(
    const float* __restrict__ x, const float* __restrict__ W1,
    const int2* __restrict__ csr, const int* __restrict__ rowptr,
    const int* __restrict__ cnt, const float* __restrict__ dinv,
    const float* __restrict__ b1, const float* __restrict__ Wp,
    float4* __restrict__ gout4, float* __restrict__ hp_part){
  extern __shared__ float hl[];   // 512 nodes x 32 feats = 64 KB
  int b = blockIdx.x;
  int xcd = b & 7, idx = b >> 3;
  int graph = xcd*8 + (idx >> 2);
  int qf = idx & 3;
  int t = threadIdx.x;
  int gbase = graph*N0;
  int fp = t & 31;
  int f = qf*32 + fp;
  float wcol[10];
  #pragma unroll
  for (int k = 0; k < 10; k++) wcol[k] = W1[k*HID + f];
  for (int n = t >> 5; n < N0; n += 16){
    const float* xr = x + (gbase + n)*10;
    float acc = 0.f;
    #pragma unroll
    for (int k = 0; k < 10; k++) acc += xr[k]*wcol[k];
    hl[n*32 + fp] = acc;
  }
  __syncthreads();
  const float4* hl4 = (const float4*)hl;
  int l = t & 7, grp = t >> 3;
  float4 bb = ((const float4*)b1)[qf*8 + l];
  float4 wp = ((const float4*)Wp)[qf*8 + l];
  for (int nl = grp; nl < N0; nl += 64){
    int node = gbase + nl;
    int start = rowptr[node], c = cnt[node];
    float4 acc = make_float4(0.f,0.f,0.f,0.f);
    for (int j = 0; j < c; j++){
      int2 e = csr[start + j];
      float wgt = __int_as_float(e.y);
      float4 hv = hl4[(e.x - gbase)*8 + l];
      acc.x += wgt*hv.x; acc.y += wgt*hv.y; acc.z += wgt*hv.z; acc.w += wgt*hv.w;
    }
    float di = dinv[node], dd = di*di;
    float4 hs = hl4[nl*8 + l];
    float4 v;
    v.x = fmaxf(acc.x + hs.x*dd + bb.x, 0.f);
    v.y = fmaxf(acc.y + hs.y*dd + bb.y, 0.f);
    v.z = fmaxf(acc.z + hs.z*dd + bb.z, 0.f);
    v.w = fmaxf(acc.w + hs.w*dd + bb.w, 0.f);
    gout4[node*32 + qf*8 + l] = v;
    float contrib = v.x*wp.x + v.y*wp.y + v.z*wp.z + v.w*wp.w;
    #pragma unroll
    for (int off = 4; off; off >>= 1) contrib += __shfl_down(contrib, off, 8);
    if (l == 0) hp_part[qf*32768 + node] = contrib;
  }
}

// Levels 2/3 fused GEMM+gather (fin=128). Phase A: register-blocked GEMM
// (8 nodes/acc, each LDS-staged W value reused 8x — the R8 version read W
// per-MAC and was 5x slower). Phase B: gather neighbors from LDS h-slice.
// dyn LDS = (4096 + nper*32) floats.
__global__ __launch_bounds__(512) void k_lx_fused(
    const float* __restrict__ x, const float* __restrict__ W,
    const int2* __restrict__ csr, const int* __restrict__ rowptr,
    const int* __restrict__ cnt, const float* __restrict__ dinv,
    const float* __restrict__ bia, const float* __restrict__ Wp,
    float4* __restrict__ gout4, float* __restrict__ hp_part, int nper){
  extern __shared__ float smem[];
  float* wl = smem;                 // 128 x 32 W quarter (16 KB)
  float* hl = smem + 4096;          // nper x 32 h-slice
  int b = blockIdx.x;
  int xcd = b & 7, idx = b >> 3;
  int graph = xcd*8 + (idx >> 2);
  int qf = idx & 3;
  int t = threadIdx.x;
  int gbase = graph*nper;
  int fp = t & 31, f = qf*32 + fp, gi = t >> 5;
  for (int kk = gi; kk < 128; kk += 16) wl[kk*32 + fp] = W[kk*HID + f];
  __syncthreads();
  // phase A: 8-node register-blocked h-slice GEMM
  int npg = nper >> 4;                       // nodes per group (16 @L2, 8 @L3)
  for (int n0 = gi*npg; n0 < (gi+1)*npg; n0 += 8){
    float acc[8] = {0,0,0,0,0,0,0,0};
    const float4* xr0 = (const float4*)(x + (gbase + n0)*HID);
    for (int kk = 0; kk < 32; kk++){
      float4 xv[8];
      #pragma unroll
      for (int nd = 0; nd < 8; nd++) xv[nd] = xr0[nd*32 + kk];
      float w0 = wl[(kk*4+0)*32 + fp];
      float w1 = wl[(kk*4+1)*32 + fp];
      float w2 = wl[(kk*4+2)*32 + fp];
      float w3 = wl[(kk*4+3)*32 + fp];
      #pragma unroll
      for (int nd = 0; nd < 8; nd++)
        acc[nd] += xv[nd].x*w0 + xv[nd].y*w1 + xv[nd].z*w2 + xv[nd].w*w3;
    }
    #pragma unroll
    for (int nd = 0; nd < 8; nd++) hl[(n0+nd)*32 + fp] = acc[nd];
  }
  __syncthreads();
  // phase B: gather from LDS
  const float4* hl4 = (const float4*)hl;
  int l = t & 7, grp = t >> 3;
  float4 bb = ((const float4*)bia)[qf*8 + l];
  float4 wp = ((const float4*)Wp)[qf*8 + l];
  for (int nl = grp; nl < nper; nl += 64){
    int node = gbase + nl;
    int start = rowptr[node], c = cnt[node];
    float4 acc = make_float4(0.f,0.f,0.f,0.f);
    for (int j = 0; j < c; j++){
      int2 e = csr[start + j];
      float wgt = __int_as_float(e.y);
      float4 hv = hl4[(e.x - gbase)*8 + l];
      acc.x += wgt*hv.x; acc.y += wgt*hv.y; acc.z += wgt*hv.z; acc.w += wgt*hv.w;
    }
    float di = dinv[node], dd = di*di;
    float4 hs = hl4[nl*8 + l];
    float4 v;
    v.x = fmaxf(acc.x + hs.x*dd + bb.x, 0.f);
    v.y = fmaxf(acc.y + hs.y*dd + bb.y, 0.f);
    v.z = fmaxf(acc.z + hs.z*dd + bb.z, 0.f);
    v.w = fmaxf(acc.w + hs.w*dd + bb.w, 0.f);
    gout4[node*32 + qf*8 + l] = v;
    float contrib = v.x*wp.x + v.y*wp.y + v.z*wp.z + v.w*wp.w;
    #pragma unroll
    for (int off = 4; off; off >>= 1) contrib += __shfl_down(contrib, off, 8);
    if (l == 0) hp_part[qf*32768 + node] = contrib;
  }
}

// Per-graph mega: score (sum 4 hp quarter-partials) -> hybrid shfl/LDS
// bitonic top-k -> pooled rows + fused readout -> relabel + next topology.
// On the last level: fused readout finalize + MLP + log_softmax.
__global__ __launch_bounds__(512) void k_mega(
    const float4* __restrict__ gout4, const float* __restrict__ hp_part,
    int2* __restrict__ csr, int* __restrict__ rowptr, int* __restrict__ cnt,
    float* __restrict__ dinv, const float* __restrict__ bp,
    int2* __restrict__ edges, float4* __restrict__ xpool4,
    float* __restrict__ z, int nper, int lastlev,
    const float* __restrict__ L1W, const float* __restrict__ L1b,
    const float* __restrict__ L2W, const float* __restrict__ L2b,
    float* __restrict__ out){
  __shared__ float sv[512];
  __shared__ int   si[512];
  __shared__ float hpl[512];
  __shared__ int   map[512];
  __shared__ int   sb[512];
  __shared__ int   cur[256];
  __shared__ float dl[256];
  __shared__ float4 pmx[16][32];
  __shared__ float4 psm[16][32];
  __shared__ float zr[256];
  __shared__ float h1[128];
  __shared__ float h2[64];
  __shared__ float red[2];
  int g = (blockIdx.x & 7)*8 + (blockIdx.x >> 3);
  int t = threadIdx.x;
  int k = nper >> 1;
  int gbase = g*nper, ebase = g*EPG, gb2 = g*k;
  bool act = t < nper;
  if (act){
    int node = gbase + t;
    hpl[t] = hp_part[node] + hp_part[32768 + node]
           + hp_part[65536 + node] + hp_part[98304 + node];
  }
  __syncthreads();
  float v = 0.f; int idx = t;
  if (act){
    int start = rowptr[gbase + t], c = cnt[gbase + t];
    float a = 0.f;
    for (int j = 0; j < c; j++){
      int2 e = csr[start + j];
      a += __int_as_float(e.y) * hpl[e.x - gbase];
    }
    float di = dinv[gbase + t];
    v = tanhf(a + hpl[t]*di*di + bp[0]);
  }
  for (int kk = 2; kk <= nper; kk <<= 1){
    for (int jj = kk >> 1; jj > 0; jj >>= 1){
      if (jj >= 64){
        if (act){ sv[t] = v; si[t] = idx; }
        __syncthreads();
        if (act){
          int p = t ^ jj;
          float pv = sv[p]; int pi = si[p];
          bool amLower = (t & jj) == 0;
          bool dirDesc = (t & kk) == 0;
          bool betterMine = (v > pv) || (v == pv && idx < pi);
          if ((amLower == dirDesc) != betterMine){ v = pv; idx = pi; }
        }
        __syncthreads();
      } else if (act){
        float pv = __shfl_xor(v, jj);
        int   pi = __shfl_xor(idx, jj);
        bool amLower = (t & jj) == 0;
        bool dirDesc = (t & kk) == 0;
        bool betterMine = (v > pv) || (v == pv && idx < pi);
        if ((amLower == dirDesc) != betterMine){ v = pv; idx = pi; }
      }
    }
  }
  if (act){ sv[t] = v; si[t] = idx; }
  __syncthreads();
  int l = t & 31, j0 = t >> 5;
  float4 mx = make_float4(-INFINITY,-INFINITY,-INFINITY,-INFINITY);
  float4 sm = make_float4(0.f,0.f,0.f,0.f);
  for (int j = j0; j < k; j += 16){
    float val = sv[j]; int row = si[j];
    float4 hv = gout4[(gbase + row)*32 + l];
    float4 o = make_float4(hv.x*val, hv.y*val, hv.z*val, hv.w*val);
    if (!lastlev) xpool4[(gb2 + j)*32 + l] = o;
    mx.x = fmaxf(mx.x, o.x); mx.y = fmaxf(mx.y, o.y);
    mx.z = fmaxf(mx.z, o.z); mx.w = fmaxf(mx.w, o.w);
    sm.x += o.x; sm.y += o.y; sm.z += o.z; sm.w += o.w;
  }
  pmx[j0][l] = mx; psm[j0][l] = sm;
  __syncthreads();
  if (t < 32){
    float4 M = pmx[0][t], S = psm[0][t];
    #pragma unroll
    for (int q = 1; q < 16; q++){
      float4 m2 = pmx[q][t], s2 = psm[q][t];
      M.x = fmaxf(M.x, m2.x); M.y = fmaxf(M.y, m2.y);
      M.z = fmaxf(M.z, m2.z); M.w = fmaxf(M.w, m2.w);
      S.x += s2.x; S.y += s2.y; S.z += s2.z; S.w += s2.w;
    }
    float ki = 1.f/(float)k;
    float* zp = z + g*256;
    if (!lastlev){
      zp[t*4+0] += M.x; zp[t*4+1] += M.y; zp[t*4+2] += M.z; zp[t*4+3] += M.w;
      zp[128+t*4+0] += S.x*ki; zp[128+t*4+1] += S.y*ki;
      zp[128+t*4+2] += S.z*ki; zp[128+t*4+3] += S.w*ki;
    } else {
      zr[t*4+0] = zp[t*4+0] + M.x; zr[t*4+1] = zp[t*4+1] + M.y;
      zr[t*4+2] = zp[t*4+2] + M.z; zr[t*4+3] = zp[t*4+3] + M.w;
      zr[128+t*4+0] = zp[128+t*4+0] + S.x*ki;
      zr[128+t*4+1] = zp[128+t*4+1] + S.y*ki;
      zr[128+t*4+2] = zp[128+t*4+2] + S.z*ki;
      zr[128+t*4+3] = zp[128+t*4+3] + S.w*ki;
    }
  }
  if (lastlev){
    __syncthreads();
    if (t < 128){
      float a = L1b[t];
      for (int i = 0; i < 256; i++) a += zr[i]*L1W[i*128 + t];
      h1[t] = fmaxf(a, 0.f);
    }
    __syncthreads();
    if (t < 64){
      float a = L2b[t];
      for (int i = 0; i < 128; i++) a += h1[i]*L2W[i*64 + t];
      h2[t] = fmaxf(a, 0.f);
    }
    __syncthreads();
    if (t == 0){
      float mxv = -INFINITY;
      for (int i = 0; i < 64; i++) mxv = fmaxf(mxv, h2[i]);
      float s = 0.f;
      for (int i = 0; i < 64; i++) s += expf(h2[i] - mxv);
      red[0] = mxv; red[1] = logf(s);
    }
    __syncthreads();
    if (t < 64) out[g*64 + t] = h2[t] - red[0] - red[1];
    return;
  }
  if (act) map[t] = -1;
  if (t < k) sb[t] = 0;
  __syncthreads();
  if (t < k) map[si[t]] = t;
  __syncthreads();
  int2 ebuf[EIT];
  #pragma unroll
  for (int it = 0; it < EIT; it++){
    int i = ebase + it*512 + t;
    int2 e = edges[i];
    int2 ne = make_int2(-1, 0);
    if (e.x >= 0){
      int ns = map[e.x - gbase], nd = map[e.y - gbase];
      if (ns >= 0 && nd >= 0){
        ne = make_int2(gb2 + ns, gb2 + nd);
        atomicAdd(&sb[nd], 1);
      }
    }
    ebuf[it] = ne;
    edges[i] = ne;
  }
  __syncthreads();
  int vdeg = (t < k) ? sb[t] : 0;
  for (int off = 1; off < k; off <<= 1){
    int add = (t >= off && t < k) ? sb[t-off] : 0;
    __syncthreads();
    if (t < k) sb[t] += add;
    __syncthreads();
  }
  if (t < k){
    int excl = sb[t] - vdeg;
    rowptr[gb2 + t] = ebase + excl;
    cnt[gb2 + t] = vdeg;
    cur[t] = excl;
    float dv = rsqrtf((float)vdeg + 1.f);
    dl[t] = dv;
    dinv[gb2 + t] = dv;
  }
  __syncthreads();
  #pragma unroll
  for (int it = 0; it < EIT; it++){
    int2 e = ebuf[it];
    if (e.x >= 0){
      int sl = e.x - gb2, dc = e.y - gb2;
      int pos = atomicAdd(&cur[dc], 1);
      csr[ebase + pos] = make_int2(e.x, __float_as_int(dl[sl]*dl[dc]));
    }
  }
}

extern "C" void kernel_launch(void* const* d_in, const int* in_sizes, int n_in,
                              void* d_out, int out_size, void* d_ws, size_t ws_size,
                              hipStream_t stream){
  (void)in_sizes; (void)n_in; (void)out_size; (void)ws_size;
  const float* x0  = (const float*)d_in[0];
  const int*   s0  = (const int*)  d_in[1];
  const int*   d0  = (const int*)  d_in[2];
  const float* W1  = (const float*)d_in[3];  const float* b1 = (const float*)d_in[4];
  const float* W2  = (const float*)d_in[5];  const float* b2 = (const float*)d_in[6];
  const float* W3  = (const float*)d_in[7];  const float* b3 = (const float*)d_in[8];
  const float* Wp  = (const float*)d_in[9];  const float* bp = (const float*)d_in[10];
  const float* L1W = (const float*)d_in[11]; const float* L1b = (const float*)d_in[12];
  const float* L2W = (const float*)d_in[13]; const float* L2b = (const float*)d_in[14];
  float* out = (float*)d_out;

  float* w = (float*)d_ws;
  float* gout  = w; w += 32768*HID;
  float* xpA   = w; w += 16384*HID;          // level-1 pool out
  float* xpB   = w; w += 8192*HID;           // level-2 pool out
  float* dinvv = w; w += 32768;
  float* hppt  = w; w += 4*32768;            // hp quarter-partials
  float* z     = w; w += BGR*256;
  int* cnt     = (int*)w; w += 32768;
  int* rowptr  = (int*)w; w += 32768;
  int2* edges  = (int2*)w; w += 2*E_TOT;
  int2* csr    = (int2*)w; w += 2*E_TOT;

  k_topo0<<<BGR, 512, 0, stream>>>(s0, d0, edges, cnt, rowptr, dinvv, csr, z);

  // level 1: 512 -> 256
  k_l1_fused<<<256, 512, 65536, stream>>>(x0, W1, csr, rowptr, cnt, dinvv,
                                          b1, Wp, (float4*)gout, hppt);
  k_mega<<<BGR, 512, 0, stream>>>((const float4*)gout, hppt, csr, rowptr, cnt,
                                  dinvv, bp, edges, (float4*)xpA, z, 512, 0,
                                  L1W, L1b, L2W, L2b, out);
  // level 2: 256 -> 128
  k_lx_fused<<<256, 512, (4096 + 256*32)*4, stream>>>(xpA, W2, csr, rowptr, cnt,
                                                      dinvv, b2, Wp, (float4*)gout,
                                                      hppt, 256);
  k_mega<<<BGR, 512, 0, stream>>>((const float4*)gout, hppt, csr, rowptr, cnt,
                                  dinvv, bp, edges, (float4*)xpB, z, 256, 0,
                                  L1W, L1b, L2W, L2b, out);
  // level 3: 128 -> 64 (+ fused readout/MLP/log_softmax)
  k_lx_fused<<<256, 512, (4096 + 128*32)*4, stream>>>(xpB, W3, csr, rowptr, cnt,
                                                      dinvv, b3, Wp, (float4*)gout,
                                                      hppt, 128);
  k_mega<<<BGR, 512, 0, stream>>>((const float4*)gout, hppt, csr, rowptr, cnt,
                                  dinvv, bp, edges, (float4*)xpA, z, 128, 1,
                                  L1W, L1b, L2W, L2b, out);
}